// Round 1
// baseline (1177.396 us; speedup 1.0000x reference)
//
#include <hip/hip_runtime.h>

typedef unsigned short u16;
typedef u16   u16x8 __attribute__((ext_vector_type(8)));
typedef short s16x8 __attribute__((ext_vector_type(8)));
typedef float f32x4 __attribute__((ext_vector_type(4)));

// Model dims
#define NV 32000
#define NT 256
#define NC 384
#define NH 6
#define ND 64
#define NL 6
#define NB 16
#define NFF 1536
#define NM (NB*NT)          // 4096 rows
#define QKVSZ (NB*NH*NT*ND) // 1572864 elems per tensor

__device__ __forceinline__ float bf2f(u16 u){ unsigned x = ((unsigned)u)<<16; return __builtin_bit_cast(float, x); }
__device__ __forceinline__ u16 f2bf(float f){
    unsigned x = __builtin_bit_cast(unsigned, f);
    x += 0x7fffu + ((x>>16)&1u);
    return (u16)(x>>16);
}

__device__ __forceinline__ void gload_lds16(const u16* g, u16* l){
    __builtin_amdgcn_global_load_lds((const __attribute__((address_space(1))) unsigned int*)g,
                                     (__attribute__((address_space(3))) unsigned int*)l, 16, 0, 0);
}

// ---------------- embedding ----------------
__global__ __launch_bounds__(256) void embed_kernel(const int* __restrict__ ids,
        const float* __restrict__ tok, const float* __restrict__ pos, float* __restrict__ x){
    int i = blockIdx.x*256 + threadIdx.x;     // 0 .. NM*NC-1, grid exact
    int m = i / NC; int c = i - m*NC; int t = m & (NT-1);
    x[i] = tok[(size_t)ids[m]*NC + c] + pos[t*NC + c];
}

// ---------------- layernorm (one wave per row) ----------------
__global__ __launch_bounds__(256) void ln_kernel(const float* __restrict__ x,
        const float* __restrict__ sc, const float* __restrict__ bi, u16* __restrict__ out){
    int row  = blockIdx.x*4 + (threadIdx.x>>6);
    int lane = threadIdx.x & 63;
    const float* xr = x + (size_t)row*NC;
    float v[6]; float sum = 0.f, sq = 0.f;
    #pragma unroll
    for (int i=0;i<6;++i){ v[i]=xr[lane+64*i]; sum+=v[i]; sq+=v[i]*v[i]; }
    #pragma unroll
    for (int off=1; off<64; off<<=1){ sum += __shfl_xor(sum,off); sq += __shfl_xor(sq,off); }
    float mean = sum*(1.f/NC);
    float var  = sq*(1.f/NC) - mean*mean;
    float rstd = rsqrtf(var + 1e-5f);
    u16* orow = out + (size_t)row*NC;
    #pragma unroll
    for (int i=0;i<6;++i){ int c = lane+64*i; orow[c] = f2bf((v[i]-mean)*rstd*sc[c] + bi[c]); }
}

// ---------------- fp32 [R][Cc] -> bf16 [Cc][R] transpose-convert ----------------
__global__ __launch_bounds__(256) void tconv(const float* __restrict__ in, u16* __restrict__ out,
        int R, int Cc, long inBatch, int obDiv, long oS1, long oS2, int oStride){
    __shared__ float tile[32][33];
    int bz = blockIdx.z;
    const float* ib = in + (size_t)bz*inBatch;
    u16* ob = out + (size_t)(bz/obDiv)*oS1 + (size_t)(bz%obDiv)*oS2;
    int r0 = blockIdx.y*32, c0 = blockIdx.x*32;
    int tx = threadIdx.x & 31, ty = threadIdx.x >> 5;   // 32 x 8
    #pragma unroll
    for (int i=0;i<4;++i) tile[ty+8*i][tx] = ib[(size_t)(r0+ty+8*i)*Cc + (c0+tx)];
    __syncthreads();
    #pragma unroll
    for (int i=0;i<4;++i) ob[(size_t)(c0+ty+8*i)*oStride + (r0+tx)] = f2bf(tile[tx][ty+8*i]);
}

// ---------------- generic bf16 MFMA GEMM, C = A[M,K] * Bt[N,K]^T ----------------
// EPI: 0 = qkv scatter (+q scale), 1 = residual += C+bias (fp32), 2 = relu bf16, 3 = fp32 + bias
template<int EPI>
__global__ __launch_bounds__(256,2) void gemm_bt(
        const u16* __restrict__ A, const u16* __restrict__ Bt,
        const float* __restrict__ bias, float* __restrict__ resid,
        u16* __restrict__ outb, float* __restrict__ outf,
        int M, int N, int K, float qscale){
    __shared__ u16 As[128*32];
    __shared__ u16 Bs[128*32];
    int tid = threadIdx.x;
    int lane = tid & 63, wid = tid >> 6;
    int wm = wid >> 1, wn = wid & 1;
    int l15 = lane & 15, lg = lane >> 4;
    int m0 = blockIdx.y * 128, n0 = blockIdx.x * 128;
    f32x4 acc[4][4];
    #pragma unroll
    for (int a=0;a<4;++a)
        #pragma unroll
        for (int b=0;b<4;++b) acc[a][b] = f32x4{0.f,0.f,0.f,0.f};

    int nk = K >> 5;
    for (int kk = 0; kk < nk; ++kk){
        int k0 = kk << 5;
        #pragma unroll
        for (int i=0;i<2;++i){
            int o   = i*4096 + tid*16;     // byte offset within 8KB tile
            int row = o >> 6;              // 64 B per tile row (32 bf16)
            int kb  = (o & 63) >> 1;       // bf16 col within row
            gload_lds16(A  + (size_t)(m0+row)*K + (k0+kb), As + (o>>1));
            gload_lds16(Bt + (size_t)(n0+row)*K + (k0+kb), Bs + (o>>1));
        }
        asm volatile("s_waitcnt vmcnt(0)" ::: "memory");
        __syncthreads();
        s16x8 af[4], bfr[4];
        #pragma unroll
        for (int mi=0;mi<4;++mi) af[mi]  = *(const s16x8*)&As[(wm*64+mi*16+l15)*32 + lg*8];
        #pragma unroll
        for (int ni=0;ni<4;++ni) bfr[ni] = *(const s16x8*)&Bs[(wn*64+ni*16+l15)*32 + lg*8];
        #pragma unroll
        for (int mi=0;mi<4;++mi)
            #pragma unroll
            for (int ni=0;ni<4;++ni)
                acc[mi][ni] = __builtin_amdgcn_mfma_f32_16x16x32_bf16(af[mi], bfr[ni], acc[mi][ni], 0,0,0);
        __syncthreads();
    }

    #pragma unroll
    for (int mi=0;mi<4;++mi){
        #pragma unroll
        for (int ni=0;ni<4;++ni){
            #pragma unroll
            for (int r=0;r<4;++r){
                int mg = m0 + wm*64 + mi*16 + lg*4 + r;
                int ng = n0 + wn*64 + ni*16 + l15;
                float c = acc[mi][ni][r];
                if (EPI == 0){
                    int which = ng / NC; int hd = ng - which*NC;
                    int hh = hd >> 6, d = hd & 63;
                    int bb = mg >> 8, tt = mg & (NT-1);
                    float val = c * (which==0 ? qscale : 1.f);
                    outb[(size_t)which*QKVSZ + ((size_t)(bb*NH+hh)*NT + tt)*ND + d] = f2bf(val);
                } else if (EPI == 1){
                    float* p = resid + (size_t)mg*N + ng;
                    *p = *p + c + bias[ng];
                } else if (EPI == 2){
                    outb[(size_t)mg*N + ng] = f2bf(fmaxf(c + bias[ng], 0.f));
                } else {
                    outf[(size_t)mg*N + ng] = c + bias[ng];
                }
            }
        }
    }
}

// ---------------- fused causal attention, one block per (b,h) ----------------
__global__ __launch_bounds__(256,1) void attn_kernel(const u16* __restrict__ qkv, u16* __restrict__ o){
    int bh = blockIdx.x;
    int b = bh / NH, h = bh - b*NH;
    int tid = threadIdx.x, lane = tid & 63, w = tid >> 6;
    int l15 = lane & 15, lg = lane >> 4;
    __shared__ u16 Ks [256*72];
    __shared__ u16 QsP[256*72];   // Q tiles, reused as per-wave P after q-frag load
    __shared__ u16 Vt [64*264];   // V transposed [d][t]
    const u16* qb = qkv + (size_t)bh*NT*ND;
    const u16* kb = qb + QKVSZ;
    const u16* vb = kb + QKVSZ;
    #pragma unroll
    for (int it=0; it<8; ++it){
        int idx = it*256 + tid;
        int e0 = idx*8;
        int row = e0 >> 6, col = e0 & 63;
        *(u16x8*)&QsP[row*72+col] = *(const u16x8*)(qb + e0);
        *(u16x8*)&Ks [row*72+col] = *(const u16x8*)(kb + e0);
        u16x8 vv = *(const u16x8*)(vb + e0);
        #pragma unroll
        for (int j=0;j<8;++j) Vt[(col+j)*264 + row] = vv[j];
    }
    __syncthreads();
    s16x8 qf[4][2];
    #pragma unroll
    for (int mi=0;mi<4;++mi)
        #pragma unroll
        for (int ks=0;ks<2;++ks)
            qf[mi][ks] = *(const s16x8*)&QsP[(w*64+mi*16+l15)*72 + ks*32 + lg*8];
    __syncthreads();
    u16* Pw = &QsP[w*64*72];

    f32x4 oacc[4][4]; float l_[4][4];
    #pragma unroll
    for (int a=0;a<4;++a)
        #pragma unroll
        for (int c=0;c<4;++c){ oacc[a][c]=f32x4{0.f,0.f,0.f,0.f}; l_[a][c]=0.f; }

    for (int kt=0; kt<=w; ++kt){
        f32x4 sacc[4][4];
        #pragma unroll
        for (int a=0;a<4;++a)
            #pragma unroll
            for (int c=0;c<4;++c) sacc[a][c]=f32x4{0.f,0.f,0.f,0.f};
        #pragma unroll
        for (int ks=0;ks<2;++ks){
            s16x8 kf[4];
            #pragma unroll
            for (int ni=0;ni<4;++ni)
                kf[ni] = *(const s16x8*)&Ks[(kt*64+ni*16+l15)*72 + ks*32 + lg*8];
            #pragma unroll
            for (int mi=0;mi<4;++mi)
                #pragma unroll
                for (int ni=0;ni<4;++ni)
                    sacc[mi][ni] = __builtin_amdgcn_mfma_f32_16x16x32_bf16(qf[mi][ks], kf[ni], sacc[mi][ni], 0,0,0);
        }
        if (kt == w){
            #pragma unroll
            for (int mi=0;mi<4;++mi)
                #pragma unroll
                for (int ni=0;ni<4;++ni)
                    #pragma unroll
                    for (int r=0;r<4;++r)
                        if (ni*16+l15 > mi*16+lg*4+r) sacc[mi][ni][r] = -1e30f;
        }
        // exp (no max-sub: scores are O(1), masked -> exp==0), row sums, write P
        #pragma unroll
        for (int mi=0;mi<4;++mi){
            #pragma unroll
            for (int r=0;r<4;++r){
                float rs = 0.f;
                #pragma unroll
                for (int ni=0;ni<4;++ni){
                    float p = __expf(sacc[mi][ni][r]);
                    sacc[mi][ni][r] = p;
                    rs += p;
                }
                rs += __shfl_xor(rs,1); rs += __shfl_xor(rs,2);
                rs += __shfl_xor(rs,4); rs += __shfl_xor(rs,8);
                l_[mi][r] += rs;
                #pragma unroll
                for (int ni=0;ni<4;++ni)
                    Pw[(mi*16+lg*4+r)*72 + ni*16+l15] = f2bf(sacc[mi][ni][r]);
            }
        }
        // PV
        #pragma unroll
        for (int ks=0;ks<2;++ks){
            s16x8 pf[4], vf[4];
            #pragma unroll
            for (int mi=0;mi<4;++mi) pf[mi] = *(const s16x8*)&Pw[(mi*16+l15)*72 + ks*32 + lg*8];
            #pragma unroll
            for (int ni=0;ni<4;++ni) vf[ni] = *(const s16x8*)&Vt[(ni*16+l15)*264 + kt*64 + ks*32 + lg*8];
            #pragma unroll
            for (int mi=0;mi<4;++mi)
                #pragma unroll
                for (int ni=0;ni<4;++ni)
                    oacc[mi][ni] = __builtin_amdgcn_mfma_f32_16x16x32_bf16(pf[mi], vf[ni], oacc[mi][ni], 0,0,0);
        }
    }
    #pragma unroll
    for (int mi=0;mi<4;++mi)
        #pragma unroll
        for (int ni=0;ni<4;++ni)
            #pragma unroll
            for (int r=0;r<4;++r){
                int t = w*64 + mi*16 + lg*4 + r;
                int d = ni*16 + l15;
                float val = oacc[mi][ni][r] / l_[mi][r];
                o[((size_t)(b*NT + t))*NC + h*ND + d] = f2bf(val);
            }
}

// ---------------- loss ----------------
__global__ __launch_bounds__(256) void loss_rows(const float* __restrict__ logits,
        const int* __restrict__ y, float* __restrict__ partial){
    int row = blockIdx.x;
    const float* lr = logits + (size_t)row*NV;
    int tid = threadIdx.x;
    float m = -1e30f, s = 0.f;
    for (int c = tid; c < NV; c += 256){
        float x = lr[c];
        float mn = fmaxf(m, x);
        s = s*__expf(m-mn) + __expf(x-mn);
        m = mn;
    }
    #pragma unroll
    for (int off=1; off<64; off<<=1){
        float mo = __shfl_xor(m, off);
        float so = __shfl_xor(s, off);
        float mn = fmaxf(m, mo);
        s = s*__expf(m-mn) + so*__expf(mo-mn);
        m = mn;
    }
    __shared__ float ms[4], ss[4];
    if ((tid&63)==0){ ms[tid>>6]=m; ss[tid>>6]=s; }
    __syncthreads();
    if (tid==0){
        float M = ms[0], S = ss[0];
        #pragma unroll
        for (int i=1;i<4;++i){
            float mn = fmaxf(M, ms[i]);
            S = S*__expf(M-mn) + ss[i]*__expf(ms[i]-mn);
            M = mn;
        }
        partial[row] = M + logf(S) - lr[y[row]];
    }
}

__global__ __launch_bounds__(256) void loss_final(const float* __restrict__ partial, float* __restrict__ out){
    int tid = threadIdx.x;
    float s = 0.f;
    for (int i = tid; i < NM; i += 256) s += partial[i];
    #pragma unroll
    for (int off=1; off<64; off<<=1) s += __shfl_xor(s, off);
    __shared__ float ss[4];
    if ((tid&63)==0) ss[tid>>6]=s;
    __syncthreads();
    if (tid==0) out[0] = (ss[0]+ss[1]+ss[2]+ss[3]) * (1.f/NM);
}

// ---------------- launch ----------------
extern "C" void kernel_launch(void* const* d_in, const int* in_sizes, int n_in,
                              void* d_out, int out_size, void* d_ws, size_t ws_size,
                              hipStream_t stream){
    const int*   x_ids = (const int*)  d_in[0];
    const int*   y_ids = (const int*)  d_in[1];
    const float* tok   = (const float*)d_in[2];
    const float* pos   = (const float*)d_in[3];
    const float* Wq    = (const float*)d_in[4];
    const float* Wk    = (const float*)d_in[5];
    const float* Wv    = (const float*)d_in[6];
    const float* Wo    = (const float*)d_in[7];
    const float* bo    = (const float*)d_in[8];
    const float* ln1s  = (const float*)d_in[9];
    const float* ln1b  = (const float*)d_in[10];
    const float* ln2s  = (const float*)d_in[11];
    const float* ln2b  = (const float*)d_in[12];
    const float* W1    = (const float*)d_in[13];
    const float* b1    = (const float*)d_in[14];
    const float* W2    = (const float*)d_in[15];
    const float* b2    = (const float*)d_in[16];
    const float* lnfs  = (const float*)d_in[17];
    const float* lnfb  = (const float*)d_in[18];
    const float* Wh    = (const float*)d_in[19];
    const float* bh    = (const float*)d_in[20];

    float* logits = (float*)d_out;
    float* lossp  = logits + (size_t)NM*NV;

    char* ws = (char*)d_ws;
    auto alloc = [&](size_t bytes)->char*{ char* p = ws; ws += (bytes + 255) & ~(size_t)255; return p; };
    float* xf    = (float*)alloc((size_t)NM*NC*4);
    u16*   hbf   = (u16*)  alloc((size_t)NM*NC*2);
    u16*   qkvb  = (u16*)  alloc((size_t)3*QKVSZ*2);
    u16*   obf   = (u16*)  alloc((size_t)NM*NC*2);
    u16*   f1bf  = (u16*)  alloc((size_t)NM*NFF*2);
    u16*   qkvw  = (u16*)  alloc((size_t)NL*1152*NC*2);
    u16*   wot   = (u16*)  alloc((size_t)NL*NC*NC*2);
    u16*   w1t   = (u16*)  alloc((size_t)NL*NFF*NC*2);
    u16*   w2t   = (u16*)  alloc((size_t)NL*NC*NFF*2);
    u16*   wht   = (u16*)  alloc((size_t)NV*NC*2);
    float* part  = (float*)alloc((size_t)NM*4);

    const float qscale = 0.051031036307982884f;   // 384^-0.5

    // ---- weight conversion ----
    // Wq/Wk/Wv: per (l,h) transpose [C,D] -> rows (h*64+d) of [1152][384]
    tconv<<<dim3(2,12,36),256,0,stream>>>(Wq, qkvw + 0*(NC*NC), NC, ND, (long)NC*ND, NH, (long)1152*NC, (long)ND*NC, NC);
    tconv<<<dim3(2,12,36),256,0,stream>>>(Wk, qkvw + 1*(NC*NC), NC, ND, (long)NC*ND, NH, (long)1152*NC, (long)ND*NC, NC);
    tconv<<<dim3(2,12,36),256,0,stream>>>(Wv, qkvw + 2*(NC*NC), NC, ND, (long)NC*ND, NH, (long)1152*NC, (long)ND*NC, NC);
    tconv<<<dim3(12,12,6),256,0,stream>>>(Wo, wot, NC, NC, (long)NC*NC, 1, (long)NC*NC, 0, NC);
    tconv<<<dim3(48,12,6),256,0,stream>>>(W1, w1t, NC, NFF, (long)NC*NFF, 1, (long)NFF*NC, 0, NC);
    tconv<<<dim3(12,48,6),256,0,stream>>>(W2, w2t, NFF, NC, (long)NFF*NC, 1, (long)NC*NFF, 0, NFF);
    tconv<<<dim3(1000,12,1),256,0,stream>>>(Wh, wht, NC, NV, 0, 1, 0, 0, NC);

    // ---- forward ----
    embed_kernel<<<NM*NC/256,256,0,stream>>>(x_ids, tok, pos, xf);
    for (int l = 0; l < NL; ++l){
        ln_kernel<<<NM/4,256,0,stream>>>(xf, ln1s + l*NC, ln1b + l*NC, hbf);
        gemm_bt<0><<<dim3(1152/128, NM/128),256,0,stream>>>(hbf, qkvw + (size_t)l*1152*NC,
                nullptr, nullptr, qkvb, nullptr, NM, 1152, NC, qscale);
        attn_kernel<<<NB*NH,256,0,stream>>>(qkvb, obf);
        gemm_bt<1><<<dim3(NC/128, NM/128),256,0,stream>>>(obf, wot + (size_t)l*NC*NC,
                bo + l*NC, xf, nullptr, nullptr, NM, NC, NC, 0.f);
        ln_kernel<<<NM/4,256,0,stream>>>(xf, ln2s + l*NC, ln2b + l*NC, hbf);
        gemm_bt<2><<<dim3(NFF/128, NM/128),256,0,stream>>>(hbf, w1t + (size_t)l*NFF*NC,
                b1 + l*NFF, nullptr, f1bf, nullptr, NM, NFF, NC, 0.f);
        gemm_bt<1><<<dim3(NC/128, NM/128),256,0,stream>>>(f1bf, w2t + (size_t)l*NC*NFF,
                b2 + l*NC, xf, nullptr, nullptr, NM, NC, NFF, 0.f);
    }
    ln_kernel<<<NM/4,256,0,stream>>>(xf, lnfs, lnfb, hbf);
    gemm_bt<3><<<dim3(NV/128, NM/128),256,0,stream>>>(hbf, wht, bh,
            nullptr, nullptr, logits, NM, NV, NC, 0.f);
    loss_rows<<<NM,256,0,stream>>>(logits, y_ids, part);
    loss_final<<<1,256,0,stream>>>(part, lossp);
}

// Round 2
// 836.424 us; speedup vs baseline: 1.4077x; 1.4077x over previous
//
#include <hip/hip_runtime.h>

typedef unsigned short u16;
typedef u16   u16x8 __attribute__((ext_vector_type(8)));
typedef short s16x8 __attribute__((ext_vector_type(8)));
typedef float f32x4 __attribute__((ext_vector_type(4)));

// Model dims
#define NV 32000
#define NT 256
#define NC 384
#define NH 6
#define ND 64
#define NL 6
#define NB 16
#define NFF 1536
#define NM (NB*NT)          // 4096 rows
#define QKVSZ (NB*NH*NT*ND) // 1572864 elems per tensor
#define NSLAB (NV/64)       // 500 loss slabs per row

__device__ __forceinline__ u16 f2bf(float f){
    unsigned x = __builtin_bit_cast(unsigned, f);
    x += 0x7fffu + ((x>>16)&1u);
    return (u16)(x>>16);
}

__device__ __forceinline__ void gload_lds16(const u16* g, u16* l){
    __builtin_amdgcn_global_load_lds((const __attribute__((address_space(1))) unsigned int*)g,
                                     (__attribute__((address_space(3))) unsigned int*)l, 16, 0, 0);
}

// ---------------- embedding (float4) ----------------
__global__ __launch_bounds__(256) void embed_kernel(const int* __restrict__ ids,
        const float* __restrict__ tok, const float* __restrict__ pos, float* __restrict__ x){
    int i4 = (blockIdx.x*256 + threadIdx.x)*4;   // grid exact: NM*NC/4 threads
    int m = i4 / NC; int c = i4 - m*NC; int t = m & (NT-1);
    const float4 a = *(const float4*)(tok + (size_t)ids[m]*NC + c);
    const float4 b = *(const float4*)(pos + t*NC + c);
    *(float4*)(x + i4) = float4{a.x+b.x, a.y+b.y, a.z+b.z, a.w+b.w};
}

// ---------------- layernorm (one wave per row) ----------------
__global__ __launch_bounds__(256) void ln_kernel(const float* __restrict__ x,
        const float* __restrict__ sc, const float* __restrict__ bi, u16* __restrict__ out){
    int row  = blockIdx.x*4 + (threadIdx.x>>6);
    int lane = threadIdx.x & 63;
    const float* xr = x + (size_t)row*NC;
    float v[6]; float sum = 0.f, sq = 0.f;
    #pragma unroll
    for (int i=0;i<6;++i){ v[i]=xr[lane+64*i]; sum+=v[i]; sq+=v[i]*v[i]; }
    #pragma unroll
    for (int off=1; off<64; off<<=1){ sum += __shfl_xor(sum,off); sq += __shfl_xor(sq,off); }
    float mean = sum*(1.f/NC);
    float var  = sq*(1.f/NC) - mean*mean;
    float rstd = rsqrtf(var + 1e-5f);
    u16* orow = out + (size_t)row*NC;
    #pragma unroll
    for (int i=0;i<6;++i){ int c = lane+64*i; orow[c] = f2bf((v[i]-mean)*rstd*sc[c] + bi[c]); }
}

// ---------------- merged transpose-convert: all 7 weight tensors, 1 launch ----------------
struct TDesc {
    const float* in; u16* out;
    int Cc; int nx; int perZ; int obDiv; int oStride; int start;
    long inBatch; long oS1; long oS2; float scale;
};
struct TPack { TDesc d[7]; };

__global__ __launch_bounds__(256) void tconv_all(TPack p){
    __shared__ float tile[32][33];
    int bid = blockIdx.x;
    int e = 0;
    #pragma unroll
    for (int i=1;i<7;++i) e += (bid >= p.d[i].start) ? 1 : 0;
    TDesc D = p.d[e];
    int local = bid - D.start;
    int bz  = local / D.perZ; int rem = local - bz*D.perZ;
    int cy  = rem / D.nx;     int cx  = rem - cy*D.nx;
    int r0 = cy*32, c0 = cx*32;
    const float* ib = D.in + (size_t)bz*D.inBatch;
    u16* ob = D.out + (size_t)(bz/D.obDiv)*D.oS1 + (size_t)(bz%D.obDiv)*D.oS2;
    int tx = threadIdx.x & 31, ty = threadIdx.x >> 5;   // 32 x 8
    #pragma unroll
    for (int i=0;i<4;++i) tile[ty+8*i][tx] = ib[(size_t)(r0+ty+8*i)*D.Cc + (c0+tx)];
    __syncthreads();
    #pragma unroll
    for (int i=0;i<4;++i) ob[(size_t)(c0+ty+8*i)*D.oStride + (r0+tx)] = f2bf(tile[tx][ty+8*i]*D.scale);
}

// ---------------- generic bf16 MFMA GEMM, C = A[M,K] * Bt[N,K]^T ----------------
// EPI: 0 = qkv scatter, 1 = residual += C+bias (fp32), 2 = relu bf16, 3 = logits + loss partials
template<int EPI, int BM>
__global__ __launch_bounds__(256,2) void gemm_bt(
        const u16* __restrict__ A, const u16* __restrict__ Bt,
        const float* __restrict__ bias, float* __restrict__ resid,
        u16* __restrict__ outb, float* __restrict__ outf, float* __restrict__ lpart,
        int M, int N, int K){
    constexpr int MI = BM/32;            // acc tiles in M per wave
    __shared__ u16 As[BM*32];
    __shared__ u16 Bs[128*32];
    int tid = threadIdx.x;
    int lane = tid & 63, wid = tid >> 6;
    int wm = wid >> 1, wn = wid & 1;
    int l15 = lane & 15, lg = lane >> 4;
    int m0 = blockIdx.y * BM, n0 = blockIdx.x * 128;
    f32x4 acc[MI][4];
    #pragma unroll
    for (int a=0;a<MI;++a)
        #pragma unroll
        for (int b=0;b<4;++b) acc[a][b] = f32x4{0.f,0.f,0.f,0.f};

    int nk = K >> 5;
    for (int kk = 0; kk < nk; ++kk){
        int k0 = kk << 5;
        #pragma unroll
        for (int i=0;i<BM/64;++i){
            int o   = i*4096 + tid*16;
            int row = o >> 6;
            int kb  = (o & 63) >> 1;
            gload_lds16(A + (size_t)(m0+row)*K + (k0+kb), As + (o>>1));
        }
        #pragma unroll
        for (int i=0;i<2;++i){
            int o   = i*4096 + tid*16;
            int row = o >> 6;
            int kb  = (o & 63) >> 1;
            gload_lds16(Bt + (size_t)(n0+row)*K + (k0+kb), Bs + (o>>1));
        }
        asm volatile("s_waitcnt vmcnt(0)" ::: "memory");
        __syncthreads();
        s16x8 af[MI], bfr[4];
        #pragma unroll
        for (int mi=0;mi<MI;++mi) af[mi]  = *(const s16x8*)&As[(wm*(BM/2)+mi*16+l15)*32 + lg*8];
        #pragma unroll
        for (int ni=0;ni<4;++ni) bfr[ni] = *(const s16x8*)&Bs[(wn*64+ni*16+l15)*32 + lg*8];
        #pragma unroll
        for (int mi=0;mi<MI;++mi)
            #pragma unroll
            for (int ni=0;ni<4;++ni)
                acc[mi][ni] = __builtin_amdgcn_mfma_f32_16x16x32_bf16(af[mi], bfr[ni], acc[mi][ni], 0,0,0);
        __syncthreads();
    }

    if (EPI == 3){
        float es[MI][4];
        #pragma unroll
        for (int mi=0;mi<MI;++mi)
            #pragma unroll
            for (int r=0;r<4;++r) es[mi][r] = 0.f;
        #pragma unroll
        for (int mi=0;mi<MI;++mi)
            #pragma unroll
            for (int ni=0;ni<4;++ni)
                #pragma unroll
                for (int r=0;r<4;++r){
                    int mg = m0 + wm*(BM/2) + mi*16 + lg*4 + r;
                    int ng = n0 + wn*64 + ni*16 + l15;
                    float val = acc[mi][ni][r] + bias[ng];
                    outf[(size_t)mg*N + ng] = val;
                    es[mi][r] += __expf(val);
                }
        #pragma unroll
        for (int mi=0;mi<MI;++mi)
            #pragma unroll
            for (int r=0;r<4;++r){
                float s = es[mi][r];
                s += __shfl_xor(s,1); s += __shfl_xor(s,2);
                s += __shfl_xor(s,4); s += __shfl_xor(s,8);
                if (l15 == 0){
                    int mg = m0 + wm*(BM/2) + mi*16 + lg*4 + r;
                    lpart[(size_t)mg*NSLAB + blockIdx.x*2 + wn] = s;
                }
            }
        return;
    }

    #pragma unroll
    for (int mi=0;mi<MI;++mi){
        #pragma unroll
        for (int ni=0;ni<4;++ni){
            #pragma unroll
            for (int r=0;r<4;++r){
                int mg = m0 + wm*(BM/2) + mi*16 + lg*4 + r;
                int ng = n0 + wn*64 + ni*16 + l15;
                float c = acc[mi][ni][r];
                if (EPI == 0){
                    int which = ng / NC; int hd = ng - which*NC;
                    int hh = hd >> 6, d = hd & 63;
                    int bb = mg >> 8, tt = mg & (NT-1);
                    outb[(size_t)which*QKVSZ + ((size_t)(bb*NH+hh)*NT + tt)*ND + d] = f2bf(c);
                } else if (EPI == 1){
                    float* pp = resid + (size_t)mg*N + ng;
                    *pp = *pp + c + bias[ng];
                } else if (EPI == 2){
                    outb[(size_t)mg*N + ng] = f2bf(fmaxf(c + bias[ng], 0.f));
                }
            }
        }
    }
}

// ---------------- fused causal attention: block per (b,h,qtile64), 4 waves x 16 rows ----------------
__global__ __launch_bounds__(256,2) void attn_kernel(const u16* __restrict__ qkv, u16* __restrict__ o){
    int blk = blockIdx.x;
    int qt = blk & 3, bh = blk >> 2;
    int b = bh / NH, h = bh - b*NH;
    int tid = threadIdx.x, lane = tid & 63, w = tid >> 6;
    int l15 = lane & 15, lg = lane >> 4;
    __shared__ u16 Ks[256*72];       // K rows [key][d], padded
    __shared__ u16 Vt[64*264];       // V transposed [d][key], padded
    __shared__ u16 Ps[4][16*72];     // per-wave P tile [qrow][key64]
    const u16* qb = qkv + (size_t)bh*NT*ND;
    const u16* kb = qb + QKVSZ;
    const u16* vb = kb + QKVSZ;
    int nit = (qt+1)*2;              // staging iters: (qt+1)*64 rows of 64
    for (int it=0; it<nit; ++it){
        int idx = it*256 + tid;
        int e0 = idx*8;
        int row = e0 >> 6, col = e0 & 63;
        *(u16x8*)&Ks[row*72+col] = *(const u16x8*)(kb + e0);
        u16x8 vv = *(const u16x8*)(vb + e0);
        #pragma unroll
        for (int j=0;j<8;++j) Vt[(col+j)*264 + row] = vv[j];
    }
    // Q fragments straight from global (16 rows per wave)
    const u16* qrow = qb + (size_t)(qt*64 + w*16 + l15)*ND;
    s16x8 qf[2];
    qf[0] = *(const s16x8*)(qrow + lg*8);
    qf[1] = *(const s16x8*)(qrow + 32 + lg*8);
    __syncthreads();

    f32x4 oacc[4]; float l_[4];
    #pragma unroll
    for (int c=0;c<4;++c){ oacc[c]=f32x4{0.f,0.f,0.f,0.f}; l_[c]=0.f; }
    u16* Pw = &Ps[w][0];

    for (int kt=0; kt<=qt; ++kt){
        f32x4 sacc[4];
        #pragma unroll
        for (int c=0;c<4;++c) sacc[c]=f32x4{0.f,0.f,0.f,0.f};
        #pragma unroll
        for (int ks=0;ks<2;++ks){
            s16x8 kf[4];
            #pragma unroll
            for (int ni=0;ni<4;++ni)
                kf[ni] = *(const s16x8*)&Ks[(kt*64+ni*16+l15)*72 + ks*32 + lg*8];
            #pragma unroll
            for (int ni=0;ni<4;++ni)
                sacc[ni] = __builtin_amdgcn_mfma_f32_16x16x32_bf16(qf[ks], kf[ni], sacc[ni], 0,0,0);
        }
        if (kt == qt){
            #pragma unroll
            for (int ni=0;ni<4;++ni)
                #pragma unroll
                for (int r=0;r<4;++r)
                    if (ni*16+l15 > w*16+lg*4+r) sacc[ni][r] = -1e30f;
        }
        #pragma unroll
        for (int r=0;r<4;++r){
            float rs = 0.f;
            #pragma unroll
            for (int ni=0;ni<4;++ni){
                float p = __expf(sacc[ni][r]);
                sacc[ni][r] = p;
                rs += p;
                Pw[(lg*4+r)*72 + ni*16 + l15] = f2bf(p);
            }
            rs += __shfl_xor(rs,1); rs += __shfl_xor(rs,2);
            rs += __shfl_xor(rs,4); rs += __shfl_xor(rs,8);
            l_[r] += rs;
        }
        #pragma unroll
        for (int ks=0;ks<2;++ks){
            s16x8 pf, vf[4];
            pf = *(const s16x8*)&Pw[l15*72 + ks*32 + lg*8];
            #pragma unroll
            for (int ni=0;ni<4;++ni)
                vf[ni] = *(const s16x8*)&Vt[(ni*16+l15)*264 + kt*64 + ks*32 + lg*8];
            #pragma unroll
            for (int ni=0;ni<4;++ni)
                oacc[ni] = __builtin_amdgcn_mfma_f32_16x16x32_bf16(pf, vf[ni], oacc[ni], 0,0,0);
        }
    }
    #pragma unroll
    for (int ni=0;ni<4;++ni)
        #pragma unroll
        for (int r=0;r<4;++r){
            int t = qt*64 + w*16 + lg*4 + r;
            int d = ni*16 + l15;
            o[((size_t)(b*NT + t))*NC + h*ND + d] = f2bf(oacc[ni][r] / l_[r]);
        }
}

// ---------------- loss: reduce per-row slab partials ----------------
__global__ __launch_bounds__(256) void loss_rows2(const float* __restrict__ lpart,
        const float* __restrict__ logits, const int* __restrict__ y, float* __restrict__ rowloss){
    int row  = blockIdx.x*4 + (threadIdx.x>>6);
    int lane = threadIdx.x & 63;
    const float* pr = lpart + (size_t)row*NSLAB;
    float s = 0.f;
    for (int i = lane; i < NSLAB; i += 64) s += pr[i];
    #pragma unroll
    for (int off=1; off<64; off<<=1) s += __shfl_xor(s, off);
    if (lane==0)
        rowloss[row] = logf(s) - logits[(size_t)row*NV + y[row]];
}

__global__ __launch_bounds__(256) void loss_final(const float* __restrict__ rowloss, float* __restrict__ out){
    int tid = threadIdx.x;
    float s = 0.f;
    for (int i = tid; i < NM; i += 256) s += rowloss[i];
    #pragma unroll
    for (int off=1; off<64; off<<=1) s += __shfl_xor(s, off);
    __shared__ float ss[4];
    if ((tid&63)==0) ss[tid>>6]=s;
    __syncthreads();
    if (tid==0) out[0] = (ss[0]+ss[1]+ss[2]+ss[3]) * (1.f/NM);
}

// ---------------- launch ----------------
extern "C" void kernel_launch(void* const* d_in, const int* in_sizes, int n_in,
                              void* d_out, int out_size, void* d_ws, size_t ws_size,
                              hipStream_t stream){
    const int*   x_ids = (const int*)  d_in[0];
    const int*   y_ids = (const int*)  d_in[1];
    const float* tok   = (const float*)d_in[2];
    const float* pos   = (const float*)d_in[3];
    const float* Wq    = (const float*)d_in[4];
    const float* Wk    = (const float*)d_in[5];
    const float* Wv    = (const float*)d_in[6];
    const float* Wo    = (const float*)d_in[7];
    const float* bo    = (const float*)d_in[8];
    const float* ln1s  = (const float*)d_in[9];
    const float* ln1b  = (const float*)d_in[10];
    const float* ln2s  = (const float*)d_in[11];
    const float* ln2b  = (const float*)d_in[12];
    const float* W1    = (const float*)d_in[13];
    const float* b1    = (const float*)d_in[14];
    const float* W2    = (const float*)d_in[15];
    const float* b2    = (const float*)d_in[16];
    const float* lnfs  = (const float*)d_in[17];
    const float* lnfb  = (const float*)d_in[18];
    const float* Wh    = (const float*)d_in[19];
    const float* bh    = (const float*)d_in[20];

    float* logits = (float*)d_out;
    float* lossp  = logits + (size_t)NM*NV;

    char* ws = (char*)d_ws;
    auto alloc = [&](size_t bytes)->char*{ char* p = ws; ws += (bytes + 255) & ~(size_t)255; return p; };
    float* xf    = (float*)alloc((size_t)NM*NC*4);
    u16*   hbf   = (u16*)  alloc((size_t)NM*NC*2);
    u16*   qkvb  = (u16*)  alloc((size_t)3*QKVSZ*2);   // also reused as loss partials (8MB <= 9.4MB)
    u16*   obf   = (u16*)  alloc((size_t)NM*NC*2);
    u16*   f1bf  = (u16*)  alloc((size_t)NM*NFF*2);
    u16*   qkvw  = (u16*)  alloc((size_t)NL*1152*NC*2);
    u16*   wot   = (u16*)  alloc((size_t)NL*NC*NC*2);
    u16*   w1t   = (u16*)  alloc((size_t)NL*NFF*NC*2);
    u16*   w2t   = (u16*)  alloc((size_t)NL*NC*NFF*2);
    u16*   wht   = (u16*)  alloc((size_t)NV*NC*2);
    float* part  = (float*)alloc((size_t)NM*4);
    float* lpart = (float*)qkvb;                        // free during head gemm/loss

    const float qscale = 0.051031036307982884f;   // 384^-0.5, folded into Wq weights

    // ---- merged weight conversion: one launch ----
    TPack tp;
    // Wq/Wk/Wv: per (l,h) transpose [C,D] -> rows (h*64+d) of [1152][384]
    tp.d[0] = {Wq, qkvw + 0*(NC*NC), ND,  2,  24, NH, NC, 0,     (long)NC*ND, (long)1152*NC, (long)ND*NC, qscale};
    tp.d[1] = {Wk, qkvw + 1*(NC*NC), ND,  2,  24, NH, NC, 864,   (long)NC*ND, (long)1152*NC, (long)ND*NC, 1.f};
    tp.d[2] = {Wv, qkvw + 2*(NC*NC), ND,  2,  24, NH, NC, 1728,  (long)NC*ND, (long)1152*NC, (long)ND*NC, 1.f};
    tp.d[3] = {Wo, wot,              NC, 12, 144, 1,  NC, 2592,  (long)NC*NC, (long)NC*NC,   0,           1.f};
    tp.d[4] = {W1, w1t,             NFF, 48, 576, 1,  NC, 3456,  (long)NC*NFF,(long)NFF*NC,  0,           1.f};
    tp.d[5] = {W2, w2t,              NC, 12, 576, 1, NFF, 6912,  (long)NFF*NC,(long)NC*NFF,  0,           1.f};
    tp.d[6] = {Wh, wht,              NV,1000,12000,1, NC, 10368, 0,           0,             0,           1.f};
    tconv_all<<<22368,256,0,stream>>>(tp);

    // ---- forward ----
    embed_kernel<<<NM*NC/1024,256,0,stream>>>(x_ids, tok, pos, xf);
    for (int l = 0; l < NL; ++l){
        ln_kernel<<<NM/4,256,0,stream>>>(xf, ln1s + l*NC, ln1b + l*NC, hbf);
        gemm_bt<0,64><<<dim3(1152/128, NM/64),256,0,stream>>>(hbf, qkvw + (size_t)l*1152*NC,
                nullptr, nullptr, qkvb, nullptr, nullptr, NM, 1152, NC);
        attn_kernel<<<NB*NH*4,256,0,stream>>>(qkvb, obf);
        gemm_bt<1,64><<<dim3(NC/128, NM/64),256,0,stream>>>(obf, wot + (size_t)l*NC*NC,
                bo + l*NC, xf, nullptr, nullptr, nullptr, NM, NC, NC);
        ln_kernel<<<NM/4,256,0,stream>>>(xf, ln2s + l*NC, ln2b + l*NC, hbf);
        gemm_bt<2,64><<<dim3(NFF/128, NM/64),256,0,stream>>>(hbf, w1t + (size_t)l*NFF*NC,
                b1 + l*NFF, nullptr, f1bf, nullptr, nullptr, NM, NFF, NC);
        gemm_bt<1,64><<<dim3(NC/128, NM/64),256,0,stream>>>(f1bf, w2t + (size_t)l*NC*NFF,
                b2 + l*NC, xf, nullptr, nullptr, nullptr, NM, NC, NFF);
    }
    ln_kernel<<<NM/4,256,0,stream>>>(xf, lnfs, lnfb, hbf);
    gemm_bt<3,128><<<dim3(NV/128, NM/128),256,0,stream>>>(hbf, wht, bh,
            nullptr, nullptr, logits, lpart, NM, NV, NC);
    loss_rows2<<<NM/4,256,0,stream>>>(lpart, logits, y_ids, part);
    loss_final<<<1,256,0,stream>>>(part, lossp);
}